// Round 3
// baseline (146.641 us; speedup 1.0000x reference)
//
#include <hip/hip_runtime.h>

// ---------------- problem constants ----------------
#define T_LEN   1048576
#define NPAD    1049600            // T_LEN + 2*512
#define NFRAMES 2049
#define BATCH   8
#define NJ      (BATCH * NFRAMES)  // 16392 total frames
#define NSEG    2050               // seg rows per batch
#define SMAX    (BATCH * NSEG - 1) // 16399
#define CUT     513
#define MROWS   1026
#define MPAD    1152               // 9 tiles of 128
#define OUT_BF  (CUT * NFRAMES)
#define NJT     129                // j-tiles of 128

typedef __attribute__((ext_vector_type(8))) short bf16x8_t;
typedef __attribute__((ext_vector_type(4))) float f32x4_t;

static __device__ __forceinline__ ushort f2bf(float f) {
    union { float f; unsigned u; } a;
    a.f = f;
    unsigned r = a.u + 0x7fffu + ((a.u >> 16) & 1u);
    return (ushort)(r >> 16);
}

static __device__ __forceinline__ void gl_lds16(const ushort* g, ushort* s) {
    __builtin_amdgcn_global_load_lds(
        (__attribute__((address_space(1))) void*)g,
        (__attribute__((address_space(3))) void*)s,
        16, 0, 0);
}

// ---------------- prep 1: reflect-pad + bf16 convert ----------------
__global__ void pad_kernel(const float* __restrict__ in, ushort* __restrict__ xpad) {
    int g  = blockIdx.x * 256 + threadIdx.x;
    int b  = g / (NPAD / 8);
    int c  = g - b * (NPAD / 8);
    int i0 = c * 8;
    const float* inb = in + (size_t)b * T_LEN;
    ushort o[8];
    if (i0 >= 512 && i0 + 7 < 512 + T_LEN) {
        const float4 v0 = *(const float4*)(inb + (i0 - 512));
        const float4 v1 = *(const float4*)(inb + (i0 - 512) + 4);
        o[0]=f2bf(v0.x); o[1]=f2bf(v0.y); o[2]=f2bf(v0.z); o[3]=f2bf(v0.w);
        o[4]=f2bf(v1.x); o[5]=f2bf(v1.y); o[6]=f2bf(v1.z); o[7]=f2bf(v1.w);
    } else {
        for (int t = 0; t < 8; ++t) {
            int i = i0 + t;
            int src = (i < 512) ? (512 - i)
                    : (i < 512 + T_LEN) ? (i - 512)
                    : (2 * T_LEN + 510 - i);
            o[t] = f2bf(inb[src]);
        }
    }
    *(ulonglong2*)(xpad + (size_t)b * NPAD + i0) = *(ulonglong2*)o;
}

// ---------------- prep 2: rearrange + bf16-convert basis ----------------
__global__ void basis_kernel(const float* __restrict__ fb, ushort* __restrict__ A2) {
    int g  = blockIdx.x * 256 + threadIdx.x;
    int r  = g >> 8;
    int cq = (g & 255) * 4;
    ushort4 o;
    if (r < MROWS) {
        int f = r >> 1, h = r & 1;
        const float4 v = *(const float4*)(fb + (size_t)(f + h * CUT) * 1024 + cq);
        o = make_ushort4(f2bf(v.x), f2bf(v.y), f2bf(v.z), f2bf(v.w));
    } else {
        o = make_ushort4(0, 0, 0, 0);
    }
    *(ushort4*)(A2 + (size_t)r * 1024 + cq) = o;
}

// ---------------- GEMM (hop-split, BK=32, paired-row swizzled LDS) ----------------
// LDS row (128B = 64 elems) i of buffer X holds logical rows i and i+H (H=64 A, 72 B),
// 4 chunks of 8 elems each, physical chunk p = logical c ^ (i&7).
__global__ __launch_bounds__(256, 5) void gemm_kernel(
        const ushort* __restrict__ A2, const ushort* __restrict__ xpad,
        float* __restrict__ out, const float* __restrict__ epsp) {
    __shared__ __align__(16) ushort ldsA0[64 * 64];   // 8 KB
    __shared__ __align__(16) ushort ldsA1[64 * 64];   // 8 KB
    __shared__ __align__(16) ushort ldsB [72 * 64];   // 9 KB

    // XCD swizzle: all 9 m-blocks of a j-tile share bid%8 (same XCD under round-robin)
    const int bid = blockIdx.x;
    const int jt  = (bid / 72) * 8 + (bid & 7);
    const int mt  = (bid >> 3) % 9;
    if (jt >= NJT) return;                     // uniform early-exit (before any barrier)

    const int tid  = threadIdx.x;
    const int wave = tid >> 6, lane = tid & 63;
    const int quad = lane >> 4, l15 = lane & 15;
    const int m0 = mt * 128;
    const int j0 = jt * 128;
    const int wm = (wave >> 1) * 64;
    const int wj = (wave & 1) * 64;

    const int b0 = j0 / NFRAMES;
    const int S0 = j0 + b0;

    // ---- staging lane decomposition ----
    const int li   = lane >> 3;            // row within 8-row issue group
    const int lc   = (lane & 7) ^ li;      // logical chunk 0..7
    const int half = lc >> 2;              // which paired row
    const int kch8 = (lc & 3) * 8;         // k offset within 32-col window

    // A issues: wave handles q = 2w, 2w+1 (8 issues cover 64 LDS rows)
    int aoff[2];
    for (int t = 0; t < 2; ++t) {
        const int q = wave * 2 + t;
        const int arow = (8 * q + li) + 64 * half;
        aoff[t] = (m0 + arow) * 1024 + kch8;
    }
    // B issues: q = 2w, 2w+1, and wave0 also q=8 (9 issues cover 72 LDS rows)
    int boff[2], boffx = 0;
    for (int t = 0; t < 2; ++t) {
        const int q = wave * 2 + t;
        int S = S0 + (8 * q + li) + 72 * half; if (S > SMAX) S = SMAX;
        int bb = S / NSEG, ss = S - bb * NSEG;
        boff[t] = bb * NPAD + ss * 512 + kch8;
    }
    {
        int S = S0 + (64 + li) + 72 * half; if (S > SMAX) S = SMAX;
        int bb = S / NSEG, ss = S - bb * NSEG;
        boffx = bb * NPAD + ss * 512 + kch8;
    }

    // ---- fragment LDS addresses (loop-invariant, elems) ----
    int addrA[4], addrB0[4], addrB1[4];
    for (int i = 0; i < 4; ++i) {
        const int m  = wm + i * 16 + l15;
        const int lr = m & 63;
        const int p  = (((m >> 6) << 2) + quad) ^ (lr & 7);
        addrA[i] = lr * 64 + p * 8;
    }
    for (int jx = 0; jx < 4; ++jx) {
        const int j  = j0 + wj + jx * 16 + l15;
        const int r0 = wj + jx * 16 + l15 + (j / NFRAMES - b0);
        const int r1 = r0 + 1;
        const int lr0 = (r0 >= 72) ? r0 - 72 : r0;
        const int lr1 = (r1 >= 72) ? r1 - 72 : r1;
        const int p0  = (((r0 >= 72) ? 4 : 0) + quad) ^ (lr0 & 7);
        const int p1  = (((r1 >= 72) ? 4 : 0) + quad) ^ (lr1 & 7);
        addrB0[jx] = lr0 * 64 + p0 * 8;
        addrB1[jx] = lr1 * 64 + p1 * 8;
    }

    f32x4_t acc[4][4] = {};

    for (int kt = 0; kt < 16; ++kt) {
        const int k32 = kt * 32;
        __syncthreads();
        #pragma unroll
        for (int t = 0; t < 2; ++t) {
            const int q = wave * 2 + t;
            gl_lds16(A2 + aoff[t] + k32,        &ldsA0[q * 512]);
            gl_lds16(A2 + aoff[t] + 512 + k32,  &ldsA1[q * 512]);
            gl_lds16(xpad + boff[t] + k32,      &ldsB [q * 512]);
        }
        if (wave == 0) gl_lds16(xpad + boffx + k32, &ldsB[8 * 512]);
        __syncthreads();

        bf16x8_t a0[4], a1[4], bf0[4], bf1[4];
        #pragma unroll
        for (int i = 0; i < 4; ++i) {
            a0[i] = *(const bf16x8_t*)&ldsA0[addrA[i]];
            a1[i] = *(const bf16x8_t*)&ldsA1[addrA[i]];
        }
        #pragma unroll
        for (int jx = 0; jx < 4; ++jx) {
            bf0[jx] = *(const bf16x8_t*)&ldsB[addrB0[jx]];
            bf1[jx] = *(const bf16x8_t*)&ldsB[addrB1[jx]];
        }
        #pragma unroll
        for (int i = 0; i < 4; ++i)
            #pragma unroll
            for (int jx = 0; jx < 4; ++jx) {
                acc[i][jx] = __builtin_amdgcn_mfma_f32_16x16x32_bf16(
                    a0[i], bf0[jx], acc[i][jx], 0, 0, 0);
                acc[i][jx] = __builtin_amdgcn_mfma_f32_16x16x32_bf16(
                    a1[i], bf1[jx], acc[i][jx], 0, 0, 0);
            }
    }

    // ---- epilogue: C/D col=lane&15 (j), row=quad*4+reg (M) ----
    const float eps = *epsp;
    for (int tj = 0; tj < 4; ++tj) {
        const int j = j0 + wj + tj * 16 + l15;
        if (j >= NJ) continue;
        const int b = j / NFRAMES;
        const int n = j - b * NFRAMES;
        float* ob = out + (size_t)b * OUT_BF + n;
        for (int ti = 0; ti < 4; ++ti) {
            const int M  = m0 + wm + ti * 16 + quad * 4;
            const int f0 = M >> 1;
            f32x4_t a = acc[ti][tj];
            if (f0 < CUT)
                ob[(size_t)f0 * NFRAMES] = sqrtf(a.x * a.x + a.y * a.y + eps);
            if (f0 + 1 < CUT)
                ob[(size_t)(f0 + 1) * NFRAMES] = sqrtf(a.z * a.z + a.w * a.w + eps);
        }
    }
}

extern "C" void kernel_launch(void* const* d_in, const int* in_sizes, int n_in,
                              void* d_out, int out_size, void* d_ws, size_t ws_size,
                              hipStream_t stream) {
    const float* in   = (const float*)d_in[0];
    const float* fb   = (const float*)d_in[1];
    const float* epsp = (const float*)d_in[2];
    float* out = (float*)d_out;

    ushort* A2   = (ushort*)d_ws;
    ushort* xpad = (ushort*)((char*)d_ws + (size_t)MPAD * 1024 * 2);

    pad_kernel<<<dim3(BATCH * (NPAD / 8) / 256), dim3(256), 0, stream>>>(in, xpad);
    basis_kernel<<<dim3(MPAD), dim3(256), 0, stream>>>(fb, A2);
    // grid: 17 groups x (8 j-tiles x 9 m-tiles); blocks with jt>=129 early-exit
    gemm_kernel<<<dim3(17 * 72), dim3(256), 0, stream>>>(A2, xpad, out, epsp);
}